// Round 1
// baseline (2652.613 us; speedup 1.0000x reference)
//
#include <hip/hip_runtime.h>

#define DIM 128
#define NCB 8
#define KSZ 2048
#define BATCH 16
#define TOK 2048
#define NTOK (BATCH * TOK)            // 32768 tokens
#define NELEM (BATCH * DIM * TOK)     // 4194304
#define T_TILE 64
#define K_CHUNK 64

// ---------------------------------------------------------------------------
// init: residual[b*TOK+t][d] = x[b][d][t]  (tiled 32x32 transpose)
// grid: 16 * 4 * 64 = 4096 blocks, 256 threads
// ---------------------------------------------------------------------------
__global__ void rvq_init_transpose(const float* __restrict__ x,
                                   float* __restrict__ res) {
    __shared__ float tile[32][33];
    int bid = blockIdx.x;
    int tt = bid & 63; int rest = bid >> 6;
    int dd = rest & 3; int b = rest >> 2;
    int t0 = tt * 32, d0 = dd * 32;
    int tx = threadIdx.x & 31, ty = threadIdx.x >> 5;   // ty 0..7

    const float* xb = x + (size_t)b * DIM * TOK;
#pragma unroll
    for (int yy = 0; yy < 4; ++yy) {
        int d = d0 + ty * 4 + yy;
        tile[ty * 4 + yy][tx] = xb[(size_t)d * TOK + t0 + tx];
    }
    __syncthreads();
    float* rb = res + (size_t)b * TOK * DIM;
#pragma unroll
    for (int yy = 0; yy < 4; ++yy) {
        int t = t0 + ty * 4 + yy;
        rb[(size_t)t * DIM + d0 + tx] = tile[tx][ty * 4 + yy];
    }
}

// ---------------------------------------------------------------------------
// cnorm[s][k] = sum_d cb[s][k][d]^2 ; also zero loss accumulator
// grid: 16384/256 = 64 blocks
// ---------------------------------------------------------------------------
__global__ void rvq_cnorm(const float* __restrict__ cbs,
                          float* __restrict__ cnorm,
                          float* __restrict__ loss_acc) {
    if (blockIdx.x == 0 && threadIdx.x == 0) *loss_acc = 0.0f;
    int k = blockIdx.x * 256 + threadIdx.x;   // 0..16383
    const float4* row = (const float4*)(cbs + (size_t)k * DIM);
    float s = 0.0f;
#pragma unroll
    for (int i = 0; i < DIM / 4; ++i) {
        float4 v = row[i];
        s += v.x * v.x + v.y * v.y + v.z * v.z + v.w * v.w;
    }
    cnorm[k] = s;
}

// ---------------------------------------------------------------------------
// one RVQ stage: distances + argmin + residual update + loss accumulation
// grid: NTOK/T_TILE = 512 blocks, 256 threads, 2 blocks/CU
// ---------------------------------------------------------------------------
__global__ __launch_bounds__(256, 2) void rvq_stage(
        const float* __restrict__ cb,      // (KSZ, DIM) this stage
        const float* __restrict__ cnorm,   // (KSZ) this stage
        float* __restrict__ residual,      // (NTOK, DIM)
        float* __restrict__ codes,         // d_out codes base + cb*TOK
        float* __restrict__ loss_acc) {
    __shared__ float resT[DIM][T_TILE + 4];     // 34816 B, rows 16B-aligned
    __shared__ float cT[DIM][K_CHUNK + 4];      // 34816 B
    __shared__ float rnorm_s[T_TILE];
    __shared__ float cnorm_s[K_CHUNK];
    __shared__ float minv_s[T_TILE][16];
    __shared__ int   mini_s[T_TILE][16];
    __shared__ int   best_s[T_TILE];

    const int tid = threadIdx.x;
    const int token0 = blockIdx.x * T_TILE;
    float* resg = residual + (size_t)token0 * DIM;

    // ---- stage residual tile -> LDS transposed ----
    {
        const float4* src = (const float4*)resg;
#pragma unroll
        for (int it = 0; it < 8; ++it) {
            int idx = it * 256 + tid;
            int tl = idx >> 5;              // token 0..63
            int dp = (idx & 31) << 2;       // d 0..124 step 4
            float4 v = src[idx];
            resT[dp + 0][tl] = v.x;
            resT[dp + 1][tl] = v.y;
            resT[dp + 2][tl] = v.z;
            resT[dp + 3][tl] = v.w;
        }
    }
    __syncthreads();
    if (tid < T_TILE) {
        float s = 0.0f;
        for (int d = 0; d < DIM; ++d) { float r = resT[d][tid]; s += r * r; }
        rnorm_s[tid] = s;
    }
    __syncthreads();

    const int tg = tid & 15;     // token group: tokens tg*4 .. +3
    const int kg = tid >> 4;     // k group within chunk: k kg*4 .. +3
    const int tg4 = tg * 4;
    const int kg4 = kg * 4;

    float rn[4];
#pragma unroll
    for (int i = 0; i < 4; ++i) rn[i] = rnorm_s[tg4 + i];

    float bestv[4]; int besti[4];
#pragma unroll
    for (int i = 0; i < 4; ++i) { bestv[i] = 3.4e38f; besti[i] = 0; }

    for (int kc = 0; kc < KSZ; kc += K_CHUNK) {
        // ---- stage codebook chunk -> LDS transposed ----
        {
            const float4* src = (const float4*)(cb + (size_t)kc * DIM);
#pragma unroll
            for (int it = 0; it < 8; ++it) {
                int idx = it * 256 + tid;
                int kl = idx >> 5;
                int dp = (idx & 31) << 2;
                float4 v = src[idx];
                cT[dp + 0][kl] = v.x;
                cT[dp + 1][kl] = v.y;
                cT[dp + 2][kl] = v.z;
                cT[dp + 3][kl] = v.w;
            }
            if (tid < K_CHUNK) cnorm_s[tid] = cnorm[kc + tid];
        }
        __syncthreads();

        float acc[4][4];
#pragma unroll
        for (int i = 0; i < 4; ++i)
#pragma unroll
            for (int j = 0; j < 4; ++j) acc[i][j] = 0.0f;

#pragma unroll 8
        for (int d = 0; d < DIM; ++d) {
            const float4 rv = *(const float4*)&resT[d][tg4];
            const float4 cv = *(const float4*)&cT[d][kg4];
            acc[0][0] = fmaf(rv.x, cv.x, acc[0][0]);
            acc[0][1] = fmaf(rv.x, cv.y, acc[0][1]);
            acc[0][2] = fmaf(rv.x, cv.z, acc[0][2]);
            acc[0][3] = fmaf(rv.x, cv.w, acc[0][3]);
            acc[1][0] = fmaf(rv.y, cv.x, acc[1][0]);
            acc[1][1] = fmaf(rv.y, cv.y, acc[1][1]);
            acc[1][2] = fmaf(rv.y, cv.z, acc[1][2]);
            acc[1][3] = fmaf(rv.y, cv.w, acc[1][3]);
            acc[2][0] = fmaf(rv.z, cv.x, acc[2][0]);
            acc[2][1] = fmaf(rv.z, cv.y, acc[2][1]);
            acc[2][2] = fmaf(rv.z, cv.z, acc[2][2]);
            acc[2][3] = fmaf(rv.z, cv.w, acc[2][3]);
            acc[3][0] = fmaf(rv.w, cv.x, acc[3][0]);
            acc[3][1] = fmaf(rv.w, cv.y, acc[3][1]);
            acc[3][2] = fmaf(rv.w, cv.z, acc[3][2]);
            acc[3][3] = fmaf(rv.w, cv.w, acc[3][3]);
        }

        // ---- fold into running argmin (k ascending, strict < = first-min) ----
#pragma unroll
        for (int j = 0; j < 4; ++j) {
            int k = kc + kg4 + j;
            float cn = cnorm_s[kg4 + j];
#pragma unroll
            for (int i = 0; i < 4; ++i) {
                // dist = (rnorm - 2*dot) + cnorm, matching reference assoc.
                float dist = fmaf(-2.0f, acc[i][j], rn[i]) + cn;
                if (dist < bestv[i]) { bestv[i] = dist; besti[i] = k; }
            }
        }
        __syncthreads();   // protect cT before next chunk restage
    }

    // ---- cross-thread argmin reduction ----
#pragma unroll
    for (int i = 0; i < 4; ++i) {
        minv_s[tg4 + i][kg] = bestv[i];
        mini_s[tg4 + i][kg] = besti[i];
    }
    __syncthreads();
    if (tid < T_TILE) {
        float bv = minv_s[tid][0]; int bi = mini_s[tid][0];
#pragma unroll
        for (int g = 1; g < 16; ++g) {
            float v = minv_s[tid][g]; int ii = mini_s[tid][g];
            if (v < bv || (v == bv && ii < bi)) { bv = v; bi = ii; }
        }
        best_s[tid] = bi;
        int b = token0 >> 11;               // token0 / TOK
        int t = (token0 & (TOK - 1)) + tid;
        codes[(size_t)b * (NCB * TOK) + t] = (float)bi;
    }
    __syncthreads();

    // ---- residual update + loss partial ----
    float lp = 0.0f;
    {
        float4* dst = (float4*)resg;
#pragma unroll
        for (int it = 0; it < 8; ++it) {
            int idx = it * 256 + tid;
            int tl = idx >> 5;
            int dp = (idx & 31) << 2;
            const float4 q = *(const float4*)(cb + (size_t)best_s[tl] * DIM + dp);
            float r0 = resT[dp + 0][tl] - q.x;
            float r1 = resT[dp + 1][tl] - q.y;
            float r2 = resT[dp + 2][tl] - q.z;
            float r3 = resT[dp + 3][tl] - q.w;
            float4 o; o.x = r0; o.y = r1; o.z = r2; o.w = r3;
            dst[idx] = o;
            lp += r0 * r0 + r1 * r1 + r2 * r2 + r3 * r3;
        }
    }
#pragma unroll
    for (int off = 32; off > 0; off >>= 1) lp += __shfl_down(lp, off, 64);
    if ((tid & 63) == 0) atomicAdd(loss_acc, lp);
}

// ---------------------------------------------------------------------------
// finalize: out0[b][d][t] = x[b][d][t] - residual[b*TOK+t][d]; write loss
// grid: 4096 blocks, 256 threads
// ---------------------------------------------------------------------------
__global__ void rvq_finalize(const float* __restrict__ x,
                             const float* __restrict__ res,
                             float* __restrict__ out,
                             const float* __restrict__ loss_acc,
                             float* __restrict__ loss_out) {
    __shared__ float tile[32][33];
    int bid = blockIdx.x;
    int tt = bid & 63; int rest = bid >> 6;
    int dd = rest & 3; int b = rest >> 2;
    int t0 = tt * 32, d0 = dd * 32;
    int tx = threadIdx.x & 31, ty = threadIdx.x >> 5;

    const float* rb = res + (size_t)b * TOK * DIM;
#pragma unroll
    for (int yy = 0; yy < 4; ++yy) {
        int t = t0 + ty * 4 + yy;
        tile[ty * 4 + yy][tx] = rb[(size_t)t * DIM + d0 + tx];
    }
    __syncthreads();
    const float* xb = x + (size_t)b * DIM * TOK;
    float* ob = out + (size_t)b * DIM * TOK;
#pragma unroll
    for (int yy = 0; yy < 4; ++yy) {
        int d = d0 + ty * 4 + yy;
        int t = t0 + tx;
        ob[(size_t)d * TOK + t] = xb[(size_t)d * TOK + t] - tile[tx][ty * 4 + yy];
    }
    if (bid == 0 && threadIdx.x == 0)
        *loss_out = *loss_acc * (1.0f / (float)NELEM);
}

// ---------------------------------------------------------------------------
extern "C" void kernel_launch(void* const* d_in, const int* in_sizes, int n_in,
                              void* d_out, int out_size, void* d_ws, size_t ws_size,
                              hipStream_t stream) {
    const float* x   = (const float*)d_in[0];   // (B, D, T)
    const float* cbs = (const float*)d_in[1];   // (NCB, KSZ, DIM)

    float* out      = (float*)d_out;            // (B,D,T) floats
    float* codes    = out + NELEM;              // (B,NCB,T) as float
    float* loss_out = out + NELEM + (size_t)BATCH * NCB * TOK;

    float* wsf      = (float*)d_ws;
    float* loss_acc = wsf;                       // [0]
    float* residual = wsf + 256;                 // (NTOK, DIM)
    float* cnorm    = wsf + 256 + (size_t)NTOK * DIM;  // (NCB*KSZ)

    hipLaunchKernelGGL(rvq_init_transpose, dim3(4096), dim3(256), 0, stream,
                       x, residual);
    hipLaunchKernelGGL(rvq_cnorm, dim3((NCB * KSZ) / 256), dim3(256), 0, stream,
                       cbs, cnorm, loss_acc);
    for (int cb = 0; cb < NCB; ++cb) {
        hipLaunchKernelGGL(rvq_stage, dim3(NTOK / T_TILE), dim3(256), 0, stream,
                           cbs + (size_t)cb * KSZ * DIM,
                           cnorm + (size_t)cb * KSZ,
                           residual,
                           codes + (size_t)cb * TOK,
                           loss_acc);
    }
    hipLaunchKernelGGL(rvq_finalize, dim3(4096), dim3(256), 0, stream,
                       x, residual, out, loss_acc, loss_out);
}